// Round 9
// baseline (175.194 us; speedup 1.0000x reference)
//
#include <hip/hip_runtime.h>
#include <hip/hip_bf16.h>

// ---------------------------------------------------------------------------
// phi = (lam ⊙ (rho @ C^T)) @ C, lam zero except k=1..256  => rank-256:
//   A[b,kk]  = Σ_n rho[b,n]·Ck[kk,n]        (kk=0..255, freq=kk+1)
//   phi[b,n] = Σ_kk A[b,kk]·(ms[kk]·Ck[kk,n])
// Ck[kk][n] = sqrt(2/4096)·cos(pi·(2n+1)·(kk+1)/8192)
//
// 3-dispatch pipeline (R8 4-dispatch proven 87.9 µs; this folds the split-K
// reduce into gemm1 via a completion counter — NOT a grid barrier: R7 showed
// spinning grid barriers cost ~55 µs each on 8-XCD MI355X; one-shot ACQ_REL
// arrival counters are ~free).
//   K1 build packed cos tables PB1/PB2 (fragment order)
//   K2 gemm1 split-K=8 -> bf16 partials; LAST z-block per row-tile reduces
//      its 16 rows -> PA2 packed bf16 (identical arithmetic to old K3)
//   K3 gemm2 -> phi
// gemm1 uses 1D grid, z = bid & 7: all 64 blocks of K-chunk z land on XCD z
// (round-robin bid%8 mapping), so each XCD's L2 caches one 256 KB PB1 slice.
// Fragment conventions (HW-verified m89):
//   A-frag lane(r=lane&15,g=lane>>4) holds A[row=r][k=g*8+j]
//   B-frag lane(r,g)                holds B[k=g*8+j][col=r]
//   D      lane reg                 holds D[row=g*4+reg][col=r]
// ---------------------------------------------------------------------------

using short8  = __attribute__((ext_vector_type(8))) short;
using ushort8 = __attribute__((ext_vector_type(8))) unsigned short;
using ushort4v= __attribute__((ext_vector_type(4))) unsigned short;
using f32x4   = __attribute__((ext_vector_type(4))) float;

#define KSPLIT 8

static __device__ __forceinline__ unsigned short f32_to_bf16(float f) {
    union { float f; unsigned u; } v; v.f = f;
    unsigned u = v.u;
    u += 0x7FFFu + ((u >> 16) & 1u);   // RNE
    return (unsigned short)(u >> 16);
}
static __device__ __forceinline__ float bf16_to_f32(unsigned short h) {
    union { unsigned u; float f; } v; v.u = ((unsigned)h) << 16;
    return v.f;
}

#define DCT_SCALE 0.0220970869120796f     /* sqrt(2/4096) */
#define DCT_W     3.834951969714103e-4f   /* 2*pi/16384   */

// ---------------------------------------------------------------------------
// K1: build packed cos tables (4 MB writes, 2M cos).
//  PB1[t=16 ][ns=128][lane][8] = bf16(Ck[t*16+r][ns*32+g*8+j])          (B of GEMM1)
//  PB2[tn=256][ks=8 ][lane][8] = bf16(ms[ks*32+g*8+j]·Ck[..][tn*16+r])  (B of GEMM2)
// grid 1024x256: blocks [0,512) PB1, [512,1024) PB2.
// ---------------------------------------------------------------------------
__global__ __launch_bounds__(256) void build_tables(const float* __restrict__ ms,
                                                    unsigned short* __restrict__ PB1,
                                                    unsigned short* __restrict__ PB2) {
    const int bid = blockIdx.x, tid = threadIdx.x;
    if (bid < 512) {           // ---- PB1
        int o8   = bid * 256 + tid;            // 0 .. 131071
        int lane = o8 & 63;
        int ns   = (o8 >> 6) & 127;
        int t    = o8 >> 13;
        int kk   = t * 16 + (lane & 15);
        int nb   = ns * 32 + (lane >> 4) * 8;
        ushort8 h;
        #pragma unroll
        for (int j = 0; j < 8; ++j) {
            int m = ((2 * (nb + j) + 1) * (kk + 1)) & 16383;
            h[j] = f32_to_bf16(DCT_SCALE * __cosf((float)m * DCT_W));
        }
        *(ushort8*)(PB1 + (size_t)o8 * 8) = h;
    } else {                   // ---- PB2 (ms folded in)
        int o8   = (bid - 512) * 256 + tid;    // 0 .. 131071
        int lane = o8 & 63;
        int ks   = (o8 >> 6) & 7;
        int tn   = o8 >> 9;
        int n    = tn * 16 + (lane & 15);
        int kb   = ks * 32 + (lane >> 4) * 8;
        f32x4 m0 = *(const f32x4*)(ms + kb);
        f32x4 m1 = *(const f32x4*)(ms + kb + 4);
        ushort8 h;
        #pragma unroll
        for (int j = 0; j < 8; ++j) {
            int kk = kb + j;
            int m  = ((2 * n + 1) * (kk + 1)) & 16383;
            float msv = (j < 4) ? m0[j & 3] : m1[j & 3];
            h[j] = f32_to_bf16(msv * DCT_SCALE * __cosf((float)m * DCT_W));
        }
        *(ushort8*)(PB2 + (size_t)o8 * 8) = h;
    }
}

// ---------------------------------------------------------------------------
// K2: GEMM1 + fused split-K reduction.
// grid 512 x 256 thr: bid -> (z = bid&7, x = bid>>3); block = 16 rows x 256 kk,
// K-chunk 512 (16 x BK32). Stage rho chunk coalesced -> LDS [16][520] bf16.
// After writing its partials slice, each block bumps counter[x] (ACQ_REL,
// agent scope); the 8th arriver reduces rows x*16..+15 across all z and
// packs PA2 -- byte-identical arithmetic to the former reduce_pack kernel.
// ---------------------------------------------------------------------------
__global__ __launch_bounds__(256) void gemm1(const float* __restrict__ rho,
                                             const unsigned short* __restrict__ PB1,
                                             unsigned short* __restrict__ partials,
                                             unsigned short* __restrict__ PA2,
                                             unsigned* __restrict__ counters) {
    __shared__ unsigned short As[16][520];   // pad 512->520 (stride 1040 B)
    __shared__ int is_last;

    const int tid = threadIdx.x;
    const int wn = tid >> 6, lane = tid & 63;
    const int r = lane & 15, g = lane >> 4;
    const int z = blockIdx.x & 7;        // K-chunk of 512 -> XCD affinity
    const int x = blockIdx.x >> 3;       // row-tile 0..63
    const int row0 = x * 16;

    // ---- stage 16 rows x 512 f32 -> bf16 LDS, fully coalesced (8 passes)
    #pragma unroll
    for (int s = 0; s < 8; ++s) {
        int slot = tid + s * 256;          // 0..2047
        int row = slot >> 7, qd = slot & 127;
        f32x4 v = *(const f32x4*)(rho + (size_t)(row0 + row) * 4096 + z * 512 + qd * 4);
        ushort4v h;
        h[0] = f32_to_bf16(v[0]); h[1] = f32_to_bf16(v[1]);
        h[2] = f32_to_bf16(v[2]); h[3] = f32_to_bf16(v[3]);
        *(ushort4v*)&As[row][qd * 4] = h;
    }
    __syncthreads();

    f32x4 acc[4];
    #pragma unroll
    for (int j = 0; j < 4; ++j)
        acc[j] = (f32x4){0.f, 0.f, 0.f, 0.f};

    const unsigned short* bbase = PB1 + (((size_t)(wn * 4) * 128 + z * 16) * 64 + lane) * 8;

    #pragma unroll
    for (int ks = 0; ks < 16; ++ks) {
        short8 a0 = *(const short8*)&As[r][ks * 32 + g * 8];
        short8 b[4];
        #pragma unroll
        for (int ni = 0; ni < 4; ++ni)
            b[ni] = *(const short8*)(bbase + ((size_t)ni * 128 + ks) * 64 * 8);
        #pragma unroll
        for (int ni = 0; ni < 4; ++ni)
            acc[ni] = __builtin_amdgcn_mfma_f32_16x16x32_bf16(a0, b[ni], acc[ni], 0, 0, 0);
    }

    unsigned short* outp = partials + (size_t)z * 262144;
    #pragma unroll
    for (int ni = 0; ni < 4; ++ni)
        #pragma unroll
        for (int reg = 0; reg < 4; ++reg) {
            int row = row0 + g * 4 + reg;
            int col = (wn * 4 + ni) * 16 + r;
            outp[(size_t)row * 256 + col] = f32_to_bf16(acc[ni][reg]);
        }

    // ---- completion counter: last of the 8 z-blocks reduces this row-tile
    __threadfence();                 // release our partials writes (agent)
    __syncthreads();
    if (tid == 0) {
        unsigned n = __hip_atomic_fetch_add(counters + x, 1u,
                                            __ATOMIC_ACQ_REL, __HIP_MEMORY_SCOPE_AGENT);
        is_last = (n == KSPLIT - 1u);
    }
    __syncthreads();
    if (is_last) {
        __threadfence();             // acquire side for all threads
        #pragma unroll
        for (int s = 0; s < 4; ++s) {
            int idx  = s * 256 + tid;          // 0..1023 within this row-tile
            int kk4  = idx & 63, brow = idx >> 6;
            int b    = row0 + brow;
            int kk   = kk4 * 4;
            float s0 = 0.f, s1 = 0.f, s2 = 0.f, s3 = 0.f;
            #pragma unroll
            for (int zz = 0; zz < KSPLIT; ++zz) {
                ushort4v v = *(const ushort4v*)(partials + (size_t)zz * 262144 + (size_t)b * 256 + kk);
                s0 += bf16_to_f32(v[0]); s1 += bf16_to_f32(v[1]);
                s2 += bf16_to_f32(v[2]); s3 += bf16_to_f32(v[3]);
            }
            int rr = b & 15;                    // tma == x
            int ks = kk >> 5, rem = kk & 31, gg = rem >> 3, hh = (rem >> 2) & 1;
            size_t slot = (((size_t)x * 8 + ks) * 64 + gg * 16 + rr) * 8 + hh * 4;
            ushort4v o;
            o[0] = f32_to_bf16(s0); o[1] = f32_to_bf16(s1);
            o[2] = f32_to_bf16(s2); o[3] = f32_to_bf16(s3);
            *(ushort4v*)(PA2 + slot) = o;
        }
    }
}

// ---------------------------------------------------------------------------
// K3: GEMM2  phi[b][n] = Σ_kk A[b,kk]·(ms·Ck)[kk,n]
// grid (16,16) x 512 thr: block = 64 rows x 256 n-cols, K=256 (8 x BK32).
// Pure-register, no LDS, no barriers.
// ---------------------------------------------------------------------------
__global__ __launch_bounds__(512) void gemm2(const unsigned short* __restrict__ PA2,
                                             const unsigned short* __restrict__ PB2,
                                             float* __restrict__ phi) {
    const int tid  = threadIdx.x;
    const int wave = tid >> 6, lane = tid & 63;
    const int wm = wave >> 2, wn = wave & 3;
    const int r = lane & 15, g = lane >> 4;
    const int tma0 = blockIdx.x * 4 + wm * 2;
    const int tn0  = blockIdx.y * 16 + wn * 4;

    f32x4 acc[2][4];
    #pragma unroll
    for (int i = 0; i < 2; ++i)
        #pragma unroll
        for (int j = 0; j < 4; ++j)
            acc[i][j] = (f32x4){0.f, 0.f, 0.f, 0.f};

    #pragma unroll
    for (int ks = 0; ks < 8; ++ks) {
        short8 a[2], b[4];
        #pragma unroll
        for (int mi = 0; mi < 2; ++mi)
            a[mi] = *(const short8*)(PA2 + (((size_t)(tma0 + mi) * 8 + ks) * 64 + lane) * 8);
        #pragma unroll
        for (int ni = 0; ni < 4; ++ni)
            b[ni] = *(const short8*)(PB2 + (((size_t)(tn0 + ni) * 8 + ks) * 64 + lane) * 8);
        #pragma unroll
        for (int mi = 0; mi < 2; ++mi)
            #pragma unroll
            for (int ni = 0; ni < 4; ++ni)
                acc[mi][ni] = __builtin_amdgcn_mfma_f32_16x16x32_bf16(a[mi], b[ni], acc[mi][ni], 0, 0, 0);
    }

    #pragma unroll
    for (int mi = 0; mi < 2; ++mi)
        #pragma unroll
        for (int ni = 0; ni < 4; ++ni)
            #pragma unroll
            for (int reg = 0; reg < 4; ++reg) {
                int row = (tma0 + mi) * 16 + g * 4 + reg;
                int col = (tn0 + ni) * 16 + r;
                phi[(size_t)row * 4096 + col] = acc[mi][ni][reg];
            }
}

// ---------------------------------------------------------------------------
extern "C" void kernel_launch(void* const* d_in, const int* in_sizes, int n_in,
                              void* d_out, int out_size, void* d_ws, size_t ws_size,
                              hipStream_t stream) {
    const float* rho = (const float*)d_in[0];   // [1024][4096] f32
    const float* ms  = (const float*)d_in[1];   // [256] f32
    float* phi = (float*)d_out;                 // [1024][4096] f32

    char* ws = (char*)d_ws;
    unsigned short* PB1      = (unsigned short*)(ws);                 //  2 MB
    unsigned short* PB2      = (unsigned short*)(ws + (2u << 20));    //  2 MB
    unsigned short* PA2      = (unsigned short*)(ws + (4u << 20));    // .5 MB
    unsigned short* partials = (unsigned short*)(ws + (8u << 20));    //  4 MB bf16
    unsigned*       counters = (unsigned*)      (ws + (16u << 20));   // 64 x u32

    hipMemsetAsync(counters, 0, 256, stream);   // ws poisoned 0xAA each call
    build_tables<<<1024, 256, 0, stream>>>(ms, PB1, PB2);
    gemm1       <<<512, 256, 0, stream>>>(rho, PB1, partials, PA2, counters);
    gemm2       <<<dim3(16, 16), 512, 0, stream>>>(PA2, PB2, phi);
}

// Round 10
// 109.585 us; speedup vs baseline: 1.5987x; 1.5987x over previous
//
#include <hip/hip_runtime.h>
#include <hip/hip_bf16.h>

// ---------------------------------------------------------------------------
// phi = (lam ⊙ (rho @ C^T)) @ C, lam zero except k=1..256  => rank-256:
//   A[b,kk]  = Σ_n rho[b,n]·Ck[kk,n]        (kk=0..255, freq=kk+1)
//   phi[b,n] = Σ_kk A[b,kk]·(ms[kk]·Ck[kk,n])
// Ck[kk][n] = sqrt(2/4096)·cos(pi·(2n+1)·(kk+1)/8192)
//
// 3-dispatch pipeline, NO inter-block synchronization anywhere:
//   K1 build packed cos tables PB1/PB2 (fragment order)
//   K2 gemm1 FULL-K (64 blocks x 8 waves, double-buffered LDS staging,
//      f32 accumulation over all K=4096) -> PA2 packed bf16 directly
//   K3 gemm2 -> phi
// History: R7 grid barriers cost ~55 µs each (cross-XCD spin); R9 even a
// one-shot __threadfence+counter cost ~115 µs (agent fence = L2 writeback).
// On MI355X the only cheap inter-block sync is the dispatch boundary.
// Fragment conventions (HW-verified m89):
//   A-frag lane(r=lane&15,g=lane>>4) holds A[row=r][k=g*8+j]
//   B-frag lane(r,g)                holds B[k=g*8+j][col=r]
//   D      lane reg                 holds D[row=g*4+reg][col=r]
// ---------------------------------------------------------------------------

using short8  = __attribute__((ext_vector_type(8))) short;
using ushort8 = __attribute__((ext_vector_type(8))) unsigned short;
using ushort4v= __attribute__((ext_vector_type(4))) unsigned short;
using f32x4   = __attribute__((ext_vector_type(4))) float;

static __device__ __forceinline__ unsigned short f32_to_bf16(float f) {
    union { float f; unsigned u; } v; v.f = f;
    unsigned u = v.u;
    u += 0x7FFFu + ((u >> 16) & 1u);   // RNE
    return (unsigned short)(u >> 16);
}

#define DCT_SCALE 0.0220970869120796f     /* sqrt(2/4096) */
#define DCT_W     3.834951969714103e-4f   /* 2*pi/16384   */

// ---------------------------------------------------------------------------
// K1: build packed cos tables (4 MB writes, 2M cos).
//  PB1[t=16 ][ns=128][lane][8] = bf16(Ck[t*16+r][ns*32+g*8+j])          (B of GEMM1)
//  PB2[tn=256][ks=8 ][lane][8] = bf16(ms[ks*32+g*8+j]·Ck[..][tn*16+r])  (B of GEMM2)
// grid 1024x256: blocks [0,512) PB1, [512,1024) PB2.
// ---------------------------------------------------------------------------
__global__ __launch_bounds__(256) void build_tables(const float* __restrict__ ms,
                                                    unsigned short* __restrict__ PB1,
                                                    unsigned short* __restrict__ PB2) {
    const int bid = blockIdx.x, tid = threadIdx.x;
    if (bid < 512) {           // ---- PB1
        int o8   = bid * 256 + tid;            // 0 .. 131071
        int lane = o8 & 63;
        int ns   = (o8 >> 6) & 127;
        int t    = o8 >> 13;
        int kk   = t * 16 + (lane & 15);
        int nb   = ns * 32 + (lane >> 4) * 8;
        ushort8 h;
        #pragma unroll
        for (int j = 0; j < 8; ++j) {
            int m = ((2 * (nb + j) + 1) * (kk + 1)) & 16383;
            h[j] = f32_to_bf16(DCT_SCALE * __cosf((float)m * DCT_W));
        }
        *(ushort8*)(PB1 + (size_t)o8 * 8) = h;
    } else {                   // ---- PB2 (ms folded in)
        int o8   = (bid - 512) * 256 + tid;    // 0 .. 131071
        int lane = o8 & 63;
        int ks   = (o8 >> 6) & 7;
        int tn   = o8 >> 9;
        int n    = tn * 16 + (lane & 15);
        int kb   = ks * 32 + (lane >> 4) * 8;
        f32x4 m0 = *(const f32x4*)(ms + kb);
        f32x4 m1 = *(const f32x4*)(ms + kb + 4);
        ushort8 h;
        #pragma unroll
        for (int j = 0; j < 8; ++j) {
            int kk = kb + j;
            int m  = ((2 * n + 1) * (kk + 1)) & 16383;
            float msv = (j < 4) ? m0[j & 3] : m1[j & 3];
            h[j] = f32_to_bf16(msv * DCT_SCALE * __cosf((float)m * DCT_W));
        }
        *(ushort8*)(PB2 + (size_t)o8 * 8) = h;
    }
}

// ---------------------------------------------------------------------------
// K2: GEMM1 full-K -> PA2 packed bf16, no split, no partials, no fences.
// grid 64 x 512 thr (8 waves): block = 16 rows x 256 kk, K = 4096 as
// 8 chunks of 512. Double-buffered LDS [2][16][520] bf16 (pad keeps the
// proven conflict-free residue); ONE barrier per chunk (also sequences
// buffer reuse). Wave w computes kk-tiles {2w, 2w+1}; 32 MFMA per chunk.
// Epilogue packs PA2 (8 scalar 2B stores/thread, 0.5 MB total).
// ---------------------------------------------------------------------------
__global__ __launch_bounds__(512) void gemm1(const float* __restrict__ rho,
                                             const unsigned short* __restrict__ PB1,
                                             unsigned short* __restrict__ PA2) {
    __shared__ unsigned short As[2][16][520];   // 33.3 KB

    const int tid = threadIdx.x;
    const int w = tid >> 6, lane = tid & 63;
    const int r = lane & 15, g = lane >> 4;
    const int x = blockIdx.x;            // row-tile 0..63
    const int row0 = x * 16;

    // stage chunk z into buffer buf: 16 rows x 512 f32 -> bf16, coalesced
    auto stage = [&](int z, int buf) {
        #pragma unroll
        for (int s = 0; s < 4; ++s) {
            int slot = tid + s * 512;      // 0..2047
            int row = slot >> 7, qd = slot & 127;
            f32x4 v = *(const f32x4*)(rho + (size_t)(row0 + row) * 4096 + z * 512 + qd * 4);
            ushort4v h;
            h[0] = f32_to_bf16(v[0]); h[1] = f32_to_bf16(v[1]);
            h[2] = f32_to_bf16(v[2]); h[3] = f32_to_bf16(v[3]);
            *(ushort4v*)&As[buf][row][qd * 4] = h;
        }
    };

    f32x4 acc[2];
    acc[0] = (f32x4){0.f, 0.f, 0.f, 0.f};
    acc[1] = (f32x4){0.f, 0.f, 0.f, 0.f};

    stage(0, 0);
    for (int z = 0; z < 8; ++z) {
        __syncthreads();                  // stage(z) done; compute(z-1) done
        if (z < 7) stage(z + 1, (z + 1) & 1);
        #pragma unroll
        for (int ks = 0; ks < 16; ++ks) {
            short8 a0 = *(const short8*)&As[z & 1][r][ks * 32 + g * 8];
            int ns = z * 16 + ks;
            short8 b0 = *(const short8*)(PB1 + (((size_t)(w * 2 + 0) * 128 + ns) * 64 + lane) * 8);
            short8 b1 = *(const short8*)(PB1 + (((size_t)(w * 2 + 1) * 128 + ns) * 64 + lane) * 8);
            acc[0] = __builtin_amdgcn_mfma_f32_16x16x32_bf16(a0, b0, acc[0], 0, 0, 0);
            acc[1] = __builtin_amdgcn_mfma_f32_16x16x32_bf16(a0, b1, acc[1], 0, 0, 0);
        }
    }

    // pack into PA2[tma=x][ks][lane'][8]:  element kk of row rr lives at
    //   ((x*8 + kk>>5)*64 + ((kk&31)>>3)*16 + rr)*8 + (kk&7)
    #pragma unroll
    for (int ni = 0; ni < 2; ++ni)
        #pragma unroll
        for (int reg = 0; reg < 4; ++reg) {
            int rr = g * 4 + reg;
            int kk = (w * 2 + ni) * 16 + r;
            size_t idx = (((size_t)x * 8 + (kk >> 5)) * 64 + ((kk & 31) >> 3) * 16 + rr) * 8 + (kk & 7);
            PA2[idx] = f32_to_bf16(acc[ni][reg]);
        }
}

// ---------------------------------------------------------------------------
// K3: GEMM2  phi[b][n] = Σ_kk A[b,kk]·(ms·Ck)[kk,n]
// grid (16,16) x 512 thr: block = 64 rows x 256 n-cols, K=256 (8 x BK32).
// Pure-register, no LDS, no barriers.
// ---------------------------------------------------------------------------
__global__ __launch_bounds__(512) void gemm2(const unsigned short* __restrict__ PA2,
                                             const unsigned short* __restrict__ PB2,
                                             float* __restrict__ phi) {
    const int tid  = threadIdx.x;
    const int wave = tid >> 6, lane = tid & 63;
    const int wm = wave >> 2, wn = wave & 3;
    const int r = lane & 15, g = lane >> 4;
    const int tma0 = blockIdx.x * 4 + wm * 2;
    const int tn0  = blockIdx.y * 16 + wn * 4;

    f32x4 acc[2][4];
    #pragma unroll
    for (int i = 0; i < 2; ++i)
        #pragma unroll
        for (int j = 0; j < 4; ++j)
            acc[i][j] = (f32x4){0.f, 0.f, 0.f, 0.f};

    #pragma unroll
    for (int ks = 0; ks < 8; ++ks) {
        short8 a[2], b[4];
        #pragma unroll
        for (int mi = 0; mi < 2; ++mi)
            a[mi] = *(const short8*)(PA2 + (((size_t)(tma0 + mi) * 8 + ks) * 64 + lane) * 8);
        #pragma unroll
        for (int ni = 0; ni < 4; ++ni)
            b[ni] = *(const short8*)(PB2 + (((size_t)(tn0 + ni) * 8 + ks) * 64 + lane) * 8);
        #pragma unroll
        for (int mi = 0; mi < 2; ++mi)
            #pragma unroll
            for (int ni = 0; ni < 4; ++ni)
                acc[mi][ni] = __builtin_amdgcn_mfma_f32_16x16x32_bf16(a[mi], b[ni], acc[mi][ni], 0, 0, 0);
    }

    #pragma unroll
    for (int mi = 0; mi < 2; ++mi)
        #pragma unroll
        for (int ni = 0; ni < 4; ++ni)
            #pragma unroll
            for (int reg = 0; reg < 4; ++reg) {
                int row = (tma0 + mi) * 16 + g * 4 + reg;
                int col = (tn0 + ni) * 16 + r;
                phi[(size_t)row * 4096 + col] = acc[mi][ni][reg];
            }
}

// ---------------------------------------------------------------------------
extern "C" void kernel_launch(void* const* d_in, const int* in_sizes, int n_in,
                              void* d_out, int out_size, void* d_ws, size_t ws_size,
                              hipStream_t stream) {
    const float* rho = (const float*)d_in[0];   // [1024][4096] f32
    const float* ms  = (const float*)d_in[1];   // [256] f32
    float* phi = (float*)d_out;                 // [1024][4096] f32

    char* ws = (char*)d_ws;
    unsigned short* PB1 = (unsigned short*)(ws);               //  2 MB
    unsigned short* PB2 = (unsigned short*)(ws + (2u << 20));  //  2 MB
    unsigned short* PA2 = (unsigned short*)(ws + (4u << 20));  // .5 MB

    build_tables<<<1024, 256, 0, stream>>>(ms, PB1, PB2);
    gemm1       <<<64, 512, 0, stream>>>(rho, PB1, PA2);
    gemm2       <<<dim3(16, 16), 512, 0, stream>>>(PA2, PB2, phi);
}

// Round 11
// 87.711 us; speedup vs baseline: 1.9974x; 1.2494x over previous
//
#include <hip/hip_runtime.h>
#include <hip/hip_bf16.h>

// ---------------------------------------------------------------------------
// phi = (lam ⊙ (rho @ C^T)) @ C, lam zero except k=1..256  => rank-256:
//   A[b,kk]  = Σ_n rho[b,n]·Ck[kk,n]        (kk=0..255, freq=kk+1)
//   phi[b,n] = Σ_kk A[b,kk]·(ms[kk]·Ck[kk,n])
// Ck[kk][n] = sqrt(2/4096)·cos(pi·(2n+1)·(kk+1)/8192)
//
// 4-dispatch pipeline — PROVEN OPTIMUM of this session (87.9 µs):
//   K1 build packed cos tables PB1/PB2 (fragment order)
//   K2 gemm1 split-K=8 -> bf16 partials (rho staged via LDS, 1 block barrier)
//   K3 reduce partials -> PA2 packed bf16
//   K4 gemm2 -> phi
// Structural lessons (all measured, do not revisit):
//   R7:  spinning grid barrier = ~55 µs each (cross-XCD seq_cst spin)
//   R9:  even one-shot __threadfence+counter = ~115 µs (agent fence
//        compiles to per-block L2 writeback on 8-XCD gfx950)
//   R10: full-K gemm1 with 64 blocks starves 256 CUs (+22 µs)
// => dispatch boundary is the only cheap sync; every phase must fill the chip.
// Harness floor: ~65-71 µs (256 MiB ws re-poison = 45 µs fillBufferAligned
// + d_out poison + d_in restore) dominates dur_us; kernel-sum ~23 µs vs
// ~12 µs traffic floor, remainder = 4 launch quanta.
// Fragment conventions (HW-verified m89):
//   A-frag lane(r=lane&15,g=lane>>4) holds A[row=r][k=g*8+j]
//   B-frag lane(r,g)                holds B[k=g*8+j][col=r]
//   D      lane reg                 holds D[row=g*4+reg][col=r]
// ---------------------------------------------------------------------------

using short8  = __attribute__((ext_vector_type(8))) short;
using ushort8 = __attribute__((ext_vector_type(8))) unsigned short;
using ushort4v= __attribute__((ext_vector_type(4))) unsigned short;
using f32x4   = __attribute__((ext_vector_type(4))) float;

#define KSPLIT 8

static __device__ __forceinline__ unsigned short f32_to_bf16(float f) {
    union { float f; unsigned u; } v; v.f = f;
    unsigned u = v.u;
    u += 0x7FFFu + ((u >> 16) & 1u);   // RNE
    return (unsigned short)(u >> 16);
}
static __device__ __forceinline__ float bf16_to_f32(unsigned short h) {
    union { unsigned u; float f; } v; v.u = ((unsigned)h) << 16;
    return v.f;
}

#define DCT_SCALE 0.0220970869120796f     /* sqrt(2/4096) */
#define DCT_W     3.834951969714103e-4f   /* 2*pi/16384   */

// ---------------------------------------------------------------------------
// K1: build packed cos tables (4 MB writes, 2M cos). Amortization is right:
// on-the-fly cos inside the GEMMs would be ~33M cos (computed out: net loss).
//  PB1[t=16 ][ns=128][lane][8] = bf16(Ck[t*16+r][ns*32+g*8+j])          (B of GEMM1)
//  PB2[tn=256][ks=8 ][lane][8] = bf16(ms[ks*32+g*8+j]·Ck[..][tn*16+r])  (B of GEMM2)
// grid 1024x256: blocks [0,512) PB1, [512,1024) PB2.
// ---------------------------------------------------------------------------
__global__ __launch_bounds__(256) void build_tables(const float* __restrict__ ms,
                                                    unsigned short* __restrict__ PB1,
                                                    unsigned short* __restrict__ PB2) {
    const int bid = blockIdx.x, tid = threadIdx.x;
    if (bid < 512) {           // ---- PB1
        int o8   = bid * 256 + tid;            // 0 .. 131071
        int lane = o8 & 63;
        int ns   = (o8 >> 6) & 127;
        int t    = o8 >> 13;
        int kk   = t * 16 + (lane & 15);
        int nb   = ns * 32 + (lane >> 4) * 8;
        ushort8 h;
        #pragma unroll
        for (int j = 0; j < 8; ++j) {
            int m = ((2 * (nb + j) + 1) * (kk + 1)) & 16383;
            h[j] = f32_to_bf16(DCT_SCALE * __cosf((float)m * DCT_W));
        }
        *(ushort8*)(PB1 + (size_t)o8 * 8) = h;
    } else {                   // ---- PB2 (ms folded in)
        int o8   = (bid - 512) * 256 + tid;    // 0 .. 131071
        int lane = o8 & 63;
        int ks   = (o8 >> 6) & 7;
        int tn   = o8 >> 9;
        int n    = tn * 16 + (lane & 15);
        int kb   = ks * 32 + (lane >> 4) * 8;
        f32x4 m0 = *(const f32x4*)(ms + kb);
        f32x4 m1 = *(const f32x4*)(ms + kb + 4);
        ushort8 h;
        #pragma unroll
        for (int j = 0; j < 8; ++j) {
            int kk = kb + j;
            int m  = ((2 * n + 1) * (kk + 1)) & 16383;
            float msv = (j < 4) ? m0[j & 3] : m1[j & 3];
            h[j] = f32_to_bf16(msv * DCT_SCALE * __cosf((float)m * DCT_W));
        }
        *(ushort8*)(PB2 + (size_t)o8 * 8) = h;
    }
}

// ---------------------------------------------------------------------------
// K2: GEMM1  partials[z][b][kk] = Σ_{n in chunk z} rho[b,n]·Ck[kk,n]  (bf16)
// grid (64,8) x 256 thr: block = 16 rows x 256 kk, K-chunk 512 (16 x BK32).
// Stage rho chunk coalesced -> LDS [16][520] bf16 (1040B rows: 16B-aligned,
// conflict-free residue class). ONE barrier per kernel.
// 4 waves, wave wn covers kk-tiles wn*4..wn*4+3; acc[1][4]; 64 MFMA/block.
// ---------------------------------------------------------------------------
__global__ __launch_bounds__(256) void gemm1(const float* __restrict__ rho,
                                             const unsigned short* __restrict__ PB1,
                                             unsigned short* __restrict__ partials) {
    __shared__ unsigned short As[16][520];   // pad 512->520 (stride 1040 B)

    const int tid = threadIdx.x;
    const int wn = tid >> 6, lane = tid & 63;
    const int r = lane & 15, g = lane >> 4;
    const int z = blockIdx.y;            // K-chunk of 512
    const int row0 = blockIdx.x * 16;

    // ---- stage 16 rows x 512 f32 -> bf16 LDS, fully coalesced (8 passes)
    #pragma unroll
    for (int s = 0; s < 8; ++s) {
        int slot = tid + s * 256;          // 0..2047
        int row = slot >> 7, qd = slot & 127;
        f32x4 v = *(const f32x4*)(rho + (size_t)(row0 + row) * 4096 + z * 512 + qd * 4);
        ushort4v h;
        h[0] = f32_to_bf16(v[0]); h[1] = f32_to_bf16(v[1]);
        h[2] = f32_to_bf16(v[2]); h[3] = f32_to_bf16(v[3]);
        *(ushort4v*)&As[row][qd * 4] = h;
    }
    __syncthreads();

    f32x4 acc[4];
    #pragma unroll
    for (int j = 0; j < 4; ++j)
        acc[j] = (f32x4){0.f, 0.f, 0.f, 0.f};

    const unsigned short* bbase = PB1 + (((size_t)(wn * 4) * 128 + z * 16) * 64 + lane) * 8;

    #pragma unroll
    for (int ks = 0; ks < 16; ++ks) {
        short8 a0 = *(const short8*)&As[r][ks * 32 + g * 8];
        short8 b[4];
        #pragma unroll
        for (int ni = 0; ni < 4; ++ni)
            b[ni] = *(const short8*)(bbase + ((size_t)ni * 128 + ks) * 64 * 8);
        #pragma unroll
        for (int ni = 0; ni < 4; ++ni)
            acc[ni] = __builtin_amdgcn_mfma_f32_16x16x32_bf16(a0, b[ni], acc[ni], 0, 0, 0);
    }

    unsigned short* outp = partials + (size_t)z * 262144;
    #pragma unroll
    for (int ni = 0; ni < 4; ++ni)
        #pragma unroll
        for (int reg = 0; reg < 4; ++reg) {
            int row = row0 + g * 4 + reg;
            int col = (wn * 4 + ni) * 16 + r;
            outp[(size_t)row * 256 + col] = f32_to_bf16(acc[ni][reg]);
        }
}

// ---------------------------------------------------------------------------
// K3: reduce bf16 split-K partials (f32 accum) -> PA2 packed bf16.
//  PA2[tma=64][ks=8][lane][8] = bf16(Σ_z partials[z][tma*16+r][ks*32+g*8+j])
// This dispatch earns its keep: it dedups the 16x A-re-read gemm2 would
// otherwise do, and the dispatch boundary is the only cheap sync (R7/R9).
// ---------------------------------------------------------------------------
__global__ __launch_bounds__(256) void reduce_pack(const unsigned short* __restrict__ partials,
                                                   unsigned short* __restrict__ PA2) {
    int idx = blockIdx.x * 256 + threadIdx.x;  // 0..65535
    int kk4 = idx & 63, b = idx >> 6;
    int kk  = kk4 * 4;
    float s0 = 0.f, s1 = 0.f, s2 = 0.f, s3 = 0.f;
    #pragma unroll
    for (int z = 0; z < KSPLIT; ++z) {
        ushort4v v = *(const ushort4v*)(partials + (size_t)z * 262144 + (size_t)b * 256 + kk);
        s0 += bf16_to_f32(v[0]); s1 += bf16_to_f32(v[1]);
        s2 += bf16_to_f32(v[2]); s3 += bf16_to_f32(v[3]);
    }
    int tma = b >> 4, r = b & 15;
    int ks = kk >> 5, rem = kk & 31, g = rem >> 3, h = (rem >> 2) & 1;
    size_t slot = (((size_t)tma * 8 + ks) * 64 + g * 16 + r) * 8 + h * 4;
    ushort4v o;
    o[0] = f32_to_bf16(s0); o[1] = f32_to_bf16(s1);
    o[2] = f32_to_bf16(s2); o[3] = f32_to_bf16(s3);
    *(ushort4v*)(PA2 + slot) = o;
}

// ---------------------------------------------------------------------------
// K4: GEMM2  phi[b][n] = Σ_kk A[b,kk]·(ms·Ck)[kk,n]
// grid (16,16) x 512 thr: block = 64 rows x 256 n-cols, K=256 (8 x BK32).
// Pure-register, no LDS, no barriers.
// ---------------------------------------------------------------------------
__global__ __launch_bounds__(512) void gemm2(const unsigned short* __restrict__ PA2,
                                             const unsigned short* __restrict__ PB2,
                                             float* __restrict__ phi) {
    const int tid  = threadIdx.x;
    const int wave = tid >> 6, lane = tid & 63;
    const int wm = wave >> 2, wn = wave & 3;
    const int r = lane & 15, g = lane >> 4;
    const int tma0 = blockIdx.x * 4 + wm * 2;
    const int tn0  = blockIdx.y * 16 + wn * 4;

    f32x4 acc[2][4];
    #pragma unroll
    for (int i = 0; i < 2; ++i)
        #pragma unroll
        for (int j = 0; j < 4; ++j)
            acc[i][j] = (f32x4){0.f, 0.f, 0.f, 0.f};

    #pragma unroll
    for (int ks = 0; ks < 8; ++ks) {
        short8 a[2], b[4];
        #pragma unroll
        for (int mi = 0; mi < 2; ++mi)
            a[mi] = *(const short8*)(PA2 + (((size_t)(tma0 + mi) * 8 + ks) * 64 + lane) * 8);
        #pragma unroll
        for (int ni = 0; ni < 4; ++ni)
            b[ni] = *(const short8*)(PB2 + (((size_t)(tn0 + ni) * 8 + ks) * 64 + lane) * 8);
        #pragma unroll
        for (int mi = 0; mi < 2; ++mi)
            #pragma unroll
            for (int ni = 0; ni < 4; ++ni)
                acc[mi][ni] = __builtin_amdgcn_mfma_f32_16x16x32_bf16(a[mi], b[ni], acc[mi][ni], 0, 0, 0);
    }

    #pragma unroll
    for (int mi = 0; mi < 2; ++mi)
        #pragma unroll
        for (int ni = 0; ni < 4; ++ni)
            #pragma unroll
            for (int reg = 0; reg < 4; ++reg) {
                int row = (tma0 + mi) * 16 + g * 4 + reg;
                int col = (tn0 + ni) * 16 + r;
                phi[(size_t)row * 4096 + col] = acc[mi][ni][reg];
            }
}

// ---------------------------------------------------------------------------
extern "C" void kernel_launch(void* const* d_in, const int* in_sizes, int n_in,
                              void* d_out, int out_size, void* d_ws, size_t ws_size,
                              hipStream_t stream) {
    const float* rho = (const float*)d_in[0];   // [1024][4096] f32
    const float* ms  = (const float*)d_in[1];   // [256] f32
    float* phi = (float*)d_out;                 // [1024][4096] f32

    char* ws = (char*)d_ws;
    unsigned short* PB1      = (unsigned short*)(ws);                 //  2 MB
    unsigned short* PB2      = (unsigned short*)(ws + (2u << 20));    //  2 MB
    unsigned short* PA2      = (unsigned short*)(ws + (4u << 20));    // .5 MB
    unsigned short* partials = (unsigned short*)(ws + (8u << 20));    //  4 MB bf16

    build_tables<<<1024, 256, 0, stream>>>(ms, PB1, PB2);
    gemm1       <<<dim3(64, 8), 256, 0, stream>>>(rho, PB1, partials);
    reduce_pack <<<256, 256, 0, stream>>>(partials, PA2);
    gemm2       <<<dim3(16, 16), 512, 0, stream>>>(PA2, PB2, phi);
}